// Round 2
// baseline (521.814 us; speedup 1.0000x reference)
//
#include <hip/hip_runtime.h>
#include <math.h>

#define HWD 262144   // 64*64*64
#define C_CH 128
#define B_N 2

__device__ __forceinline__ float sigmoidf_(float v) {
    return 1.0f / (1.0f + expf(-v));
}

// Cox-de Boor B-spline bases, k=3, GRID_SIZE=5, grid range [-1,1].
__device__ __forceinline__ void bspline8(float x, float* bs) {
    float g[12];
#pragma unroll
    for (int i = 0; i < 12; ++i) g[i] = (float)(i - 3) * 0.4f - 1.0f;
    float b[11];
#pragma unroll
    for (int t = 0; t < 11; ++t) b[t] = (x >= g[t] && x < g[t + 1]) ? 1.0f : 0.0f;
#pragma unroll
    for (int j = 1; j <= 3; ++j) {
#pragma unroll
        for (int t = 0; t + j < 11; ++t) {
            b[t] = (x - g[t]) / (g[t + j] - g[t]) * b[t]
                 + (g[t + j + 1] - x) / (g[t + j + 1] - g[t + 1]) * b[t + 1];
        }
    }
#pragma unroll
    for (int t = 0; t < 8; ++t) bs[t] = b[t];
}

// ---------------- Kernel 1: partial mean/max, 4 chunks per (b,c) -------------
// 1024 blocks x 256 threads; block = (bc, chunk), streams contiguous 256 KB.
// ws layout (floats): [0,1024) partial sums, [1024,2048) partial max,
// [2048,2304) catt, [2304,2560) w2 = catt*conv_w.
__global__ __launch_bounds__(256) void k1_pool(const float* __restrict__ x,
                                               float* __restrict__ ws) {
    int bid = blockIdx.x;                 // bc*4 + chunk
    int bc = bid >> 2, chunk = bid & 3;
    const float4* xp = (const float4*)(x + (size_t)bc * HWD + (size_t)chunk * 65536);
    int tid = threadIdx.x;
    float s = 0.0f, m = -INFINITY;
#pragma unroll 8
    for (int i = 0; i < 64; ++i) {
        float4 v = xp[i * 256 + tid];
        s += (v.x + v.y) + (v.z + v.w);
        m = fmaxf(m, fmaxf(fmaxf(v.x, v.y), fmaxf(v.z, v.w)));
    }
#pragma unroll
    for (int off = 32; off > 0; off >>= 1) {
        s += __shfl_xor(s, off, 64);
        m = fmaxf(m, __shfl_xor(m, off, 64));
    }
    __shared__ float ss[4], sm[4];
    int wave = tid >> 6;
    if ((tid & 63) == 0) { ss[wave] = s; sm[wave] = m; }
    __syncthreads();
    if (tid == 0) {
        ws[bid]        = (ss[0] + ss[1]) + (ss[2] + ss[3]);
        ws[1024 + bid] = fmaxf(fmaxf(sm[0], sm[1]), fmaxf(sm[2], sm[3]));
    }
}

// ---------------- Kernel 2: channel attention (tiny KAN MLP) -----------------
__global__ __launch_bounds__(512) void k2_catt(const float* ws_in,
                                               const float* __restrict__ ck1_base,
                                               const float* __restrict__ ck1_spline,
                                               const float* __restrict__ ck2_base,
                                               const float* __restrict__ ck2_spline,
                                               const float* __restrict__ conv_w,
                                               float* ws_out) {
    __shared__ float y[512];            // [0,256) y_avg, [256,512) y_max
    __shared__ float part[512 * 8];     // per-thread layer-1 partials
    __shared__ float h1silu[32];
    __shared__ float h1bs[32][8];
    __shared__ float out2[512];
    int t = threadIdx.x;
    if (t < 256) {
        y[t] = (ws_in[t * 4] + ws_in[t * 4 + 1] + ws_in[t * 4 + 2] + ws_in[t * 4 + 3])
               * (1.0f / (float)HWD);
        y[256 + t] = fmaxf(fmaxf(ws_in[1024 + t * 4],     ws_in[1024 + t * 4 + 1]),
                           fmaxf(ws_in[1024 + t * 4 + 2], ws_in[1024 + t * 4 + 3]));
    }
    __syncthreads();
    // Phase A: layer-1 contributions. t = ysel*256 + b*128 + i
    {
        int i = t & 127;
        float v = y[t];
        float sv = v * sigmoidf_(v);     // silu
        float bs[8];
        bspline8(v, bs);
#pragma unroll
        for (int r = 0; r < 8; ++r) {
            float acc = sv * ck1_base[r * 128 + i];
#pragma unroll
            for (int g = 0; g < 8; ++g)
                acc += bs[g] * ck1_spline[(r * 128 + i) * 8 + g];
            part[t * 8 + r] = acc;
        }
    }
    __syncthreads();
    // Deterministic reduce over i, then relu + silu/spline of h1.
    if (t < 32) {                        // t = ysel*16 + b*8 + r
        int ysel = t >> 4, b = (t >> 3) & 1, r = t & 7;
        int tb = ysel * 256 + b * 128;
        float acc = 0.0f;
        for (int i = 0; i < 128; ++i) acc += part[(tb + i) * 8 + r];
        float h = fmaxf(acc, 0.0f);      // relu
        h1silu[t] = h * sigmoidf_(h);
        bspline8(h, h1bs[t]);
    }
    __syncthreads();
    // Phase B: layer-2. t = ysel*256 + b*128 + o
    {
        int ysel = t >> 8, b = (t >> 7) & 1, o = t & 127;
        float acc = 0.0f;
#pragma unroll
        for (int r = 0; r < 8; ++r) {
            int hidx = ysel * 16 + b * 8 + r;
            acc += h1silu[hidx] * ck2_base[o * 8 + r];
#pragma unroll
            for (int g = 0; g < 8; ++g)
                acc += h1bs[hidx][g] * ck2_spline[(o * 8 + r) * 8 + g];
        }
        out2[t] = acc;
    }
    __syncthreads();
    if (t < 256) {                       // t = b*128 + o
        int o = t & 127;
        float catt = sigmoidf_(out2[t] + out2[256 + t]);   // avg + max paths
        ws_out[2048 + t] = catt;
        ws_out[2304 + t] = catt * conv_w[o];
    }
}

// ---------------- Kernel 3: main fused pass ---------------------------------
// Block = 128 channels x 256 contiguous voxels staged in 128 KB LDS.
// Per-channel HBM chunk = 1 KB contiguous (4x the previous 256 B).
// Block order REVERSED so the tail of x (still resident in 256 MB L3 after
// k1's ascending stream) is read first -> partial L3 hits on the re-read.
__global__ __launch_bounds__(1024) void k3_main(const float* __restrict__ x,
                                                const float* __restrict__ ws,
                                                const float* __restrict__ sk_base,
                                                const float* __restrict__ sk_spline,
                                                float* __restrict__ out) {
    __shared__ __align__(16) float xs[C_CH * 256];   // 128 KB
    __shared__ float partial[1024];
    __shared__ __align__(16) float satt[256];
    __shared__ float catts[C_CH];
    __shared__ float w2s[C_CH];
    int tid = threadIdx.x;
    int g = 2047 - (int)blockIdx.x;       // reversed order
    int b = g >> 10;                      // 1024 chunks per batch (HWD/256)
    int v0 = (g & 1023) << 8;
    if (tid < 128) {
        catts[tid] = ws[2048 + b * 128 + tid];
        w2s[tid]   = ws[2304 + b * 128 + tid];
    }
    const float* xb = x + (size_t)b * C_CH * HWD + v0;
    // Load 128x256 tile: 8192 float4, 8 per thread; one 1 KB row per wave.
#pragma unroll
    for (int m = 0; m < 8; ++m) {
        int f = m * 1024 + tid;
        int c = f >> 6;
        int j = f & 63;
        *(float4*)&xs[c * 256 + j * 4] = *(const float4*)(xb + (size_t)c * HWD + j * 4);
    }
    __syncthreads();
    // s[v] = sum_c xs[c][v] * w2[c]; 4 partials (32 channels each) per voxel.
    {
        int v = tid & 255, q = tid >> 8;
        float acc = 0.0f;
#pragma unroll
        for (int cc = 0; cc < 32; ++cc) {
            int c = q * 32 + cc;
            acc += xs[c * 256 + v] * w2s[c];
        }
        partial[tid] = acc;
    }
    __syncthreads();
    if (tid < 256) {
        float s = partial[tid] + partial[tid + 256] + partial[tid + 512] + partial[tid + 768];
        float bs[8];
        bspline8(s, bs);
        float a = s * sigmoidf_(s) * sk_base[0];
#pragma unroll
        for (int g2 = 0; g2 < 8; ++g2) a += bs[g2] * sk_spline[g2];
        satt[tid] = sigmoidf_(a);
    }
    __syncthreads();
    float* ob = out + (size_t)b * C_CH * HWD + v0;
#pragma unroll
    for (int m = 0; m < 8; ++m) {
        int f = m * 1024 + tid;
        int c = f >> 6;
        int j = f & 63;
        float4 v = *(float4*)&xs[c * 256 + j * 4];
        float4 sa = *(float4*)&satt[j * 4];
        float ca = catts[c];
        float4 o;
        o.x = v.x * ca * sa.x;
        o.y = v.y * ca * sa.y;
        o.z = v.z * ca * sa.z;
        o.w = v.w * ca * sa.w;
        *(float4*)(ob + (size_t)c * HWD + j * 4) = o;
    }
}

extern "C" void kernel_launch(void* const* d_in, const int* in_sizes, int n_in,
                              void* d_out, int out_size, void* d_ws, size_t ws_size,
                              hipStream_t stream) {
    const float* x          = (const float*)d_in[0];
    const float* ck1_base   = (const float*)d_in[1];
    const float* ck1_spline = (const float*)d_in[2];
    const float* ck2_base   = (const float*)d_in[3];
    const float* ck2_spline = (const float*)d_in[4];
    const float* conv_w     = (const float*)d_in[5];
    const float* sk_base    = (const float*)d_in[6];
    const float* sk_spline  = (const float*)d_in[7];
    float* out = (float*)d_out;
    float* ws  = (float*)d_ws;

    k1_pool<<<1024, 256, 0, stream>>>(x, ws);
    k2_catt<<<1, 512, 0, stream>>>(ws, ck1_base, ck1_spline, ck2_base, ck2_spline,
                                   conv_w, ws);
    k3_main<<<B_N * (HWD / 256), 1024, 0, stream>>>(x, ws, sk_base, sk_spline, out);
}